// Round 19
// baseline (129.267 us; speedup 1.0000x reference)
//
#include <hip/hip_runtime.h>

#define T_LEN  1024
#define D_DIM  8
#define BIGV   1e30f
#define EPSV   1e-6f
#define RB     256

// ---- tier-1 (2-row, fwd+bwd merged) constants ----
#define NT2   18          // 64-step tiles per wave (1152 local steps)
#define TS2   1152
#define NSS1  28          // 3*(4-1) + 18 = 27, padded even

// ---- tier-2 (R15-verified) constants ----
#define NTILE  17
#define TSTEPS 1088
#define NSLOT  16
#define NW3    8
#define NSS3   32

typedef _Float16 half2v __attribute__((ext_vector_type(2)));
typedef unsigned u32x4  __attribute__((ext_vector_type(4)));

__device__ __forceinline__ float dpp_shr1(float x) {   // dst[n]=src[n-1]; lane0 keeps old
  int xi = __builtin_bit_cast(int, x);
  int r = __builtin_amdgcn_update_dpp(xi, xi, 0x138, 0xf, 0xf, false);
  return __builtin_bit_cast(float, r);
}
__device__ __forceinline__ float dpp_shl1(float x) {   // dst[n]=src[n+1]; lane63 keeps old
  int xi = __builtin_bit_cast(int, x);
  int r = __builtin_amdgcn_update_dpp(xi, xi, 0x130, 0xf, 0xf, false);
  return __builtin_bit_cast(float, r);
}

#define GLOADO(dst, addr, OFF)                                             \
  asm volatile("global_load_dwordx4 %0, %1, off offset:" #OFF             \
               : "=v"(dst) : "v"(addr))

// ===========================================================================
// TIER 1: dtw13's verified per-half machinery, fwd+bwd merged in one block.
// ===========================================================================

// dist6 (R18-verified): u32 {lo: ddA, hi: ddB} at [b][slot][lt][l][q],
// slot = h*4 + w.  h: 0 fwd, 1 bwd (row r -> 1023-r, col c -> 1023-c).
// lane l of wave w owns half-local rows 128w+2l (A), +1 (B).
__global__ __launch_bounds__(256)
void dist6_kernel(const float* __restrict__ obs, const float* __restrict__ mod,
                  unsigned* __restrict__ dist) {
  const int q  = threadIdx.x & 63;
  const int wv = threadIdx.x >> 6;           // 0..3
  const int lt = blockIdx.x % NT2;
  const int lg = blockIdx.x / NT2;           // 0..15
  const int l  = lg * 4 + wv;
  const int s  = blockIdx.y;                 // 0..7
  const int h  = s >> 2;
  const int w  = s & 3;
  const int b  = blockIdx.z;
  const int t  = lt * 64 + q;
  const int R0 = 128 * w + 2 * l;            // half-local row of cell A
  const int colA = t - 2 * l;
  const int colB = colA - 1;

  float vA = __builtin_inff(), vB = __builtin_inff();
  if ((unsigned)colA < (unsigned)T_LEN) {
    const int rg = h ? (1023 - R0) : R0;
    const int cg = h ? (1023 - colA) : colA;
    const float4* o4 = (const float4*)(obs + ((size_t)b * T_LEN + rg) * D_DIM);
    const float4* m4 = (const float4*)(mod + ((size_t)b * T_LEN + cg) * D_DIM);
    float4 a0 = o4[0], a1 = o4[1], c0 = m4[0], c1 = m4[1];
    float acc = 0.f, df;
    df = a0.x - c0.x + EPSV; acc = fmaf(df, df, acc);
    df = a0.y - c0.y + EPSV; acc = fmaf(df, df, acc);
    df = a0.z - c0.z + EPSV; acc = fmaf(df, df, acc);
    df = a0.w - c0.w + EPSV; acc = fmaf(df, df, acc);
    df = a1.x - c1.x + EPSV; acc = fmaf(df, df, acc);
    df = a1.y - c1.y + EPSV; acc = fmaf(df, df, acc);
    df = a1.z - c1.z + EPSV; acc = fmaf(df, df, acc);
    df = a1.w - c1.w + EPSV; acc = fmaf(df, df, acc);
    vA = sqrtf(acc);
  }
  if ((unsigned)colB < (unsigned)T_LEN) {
    const int rg = h ? (1023 - (R0 + 1)) : (R0 + 1);
    const int cg = h ? (1023 - colB) : colB;
    const float4* o4 = (const float4*)(obs + ((size_t)b * T_LEN + rg) * D_DIM);
    const float4* m4 = (const float4*)(mod + ((size_t)b * T_LEN + cg) * D_DIM);
    float4 a0 = o4[0], a1 = o4[1], c0 = m4[0], c1 = m4[1];
    float acc = 0.f, df;
    df = a0.x - c0.x + EPSV; acc = fmaf(df, df, acc);
    df = a0.y - c0.y + EPSV; acc = fmaf(df, df, acc);
    df = a0.z - c0.z + EPSV; acc = fmaf(df, df, acc);
    df = a0.w - c0.w + EPSV; acc = fmaf(df, df, acc);
    df = a1.x - c1.x + EPSV; acc = fmaf(df, df, acc);
    df = a1.y - c1.y + EPSV; acc = fmaf(df, df, acc);
    df = a1.z - c1.z + EPSV; acc = fmaf(df, df, acc);
    df = a1.w - c1.w + EPSV; acc = fmaf(df, df, acc);
    vB = sqrtf(acc);
  }
  const unsigned hA = __builtin_bit_cast(unsigned short, (_Float16)vA);
  const unsigned hB = __builtin_bit_cast(unsigned short, (_Float16)vB);
  dist[(((size_t)(b * 8 + s) * NT2 + lt) * 64 + l) * 64 + q] = (hB << 16) | hA;
}

// R18-verified 2-row step, verbatim (w0 -> hw0 rename only).
#define DTW_STEPQ2(U, QQ)                                                  \
  {                                                                        \
    half2v hh_ = __builtin_bit_cast(half2v, (unsigned)(U));                \
    const float ddA_ = (float)hh_[0];                                      \
    const float ddB_ = (float)hh_[1];                                      \
    float bU  = dpp_shr1(bC);                                              \
    float bU2 = dpp_shr1(bP);                                              \
    bU  = lane0 ? rv  : bU;                                                \
    bU2 = lane0 ? rvo : bU2;                                               \
    float bestA = fminf(fminf(bU, bU2), aC);                               \
    if ((QQ) == 0 && LT == 0) { if (hw0 && lane0) bestA = 0.f; }           \
    const float newA = ddA_ + bestA;                                       \
    const float bestB = fminf(fminf(aC, aP), bC);                          \
    const float newB = ddB_ + bestB;                                       \
    aP = aC; aC = newA; bP = bC; bC = newB;                                \
    rvo = rv; rv = dpp_shl1(rv);                                           \
    out = dpp_shl1(out);                                                   \
    out = lane63 ? bC : out;                                               \
  }

#define DTW_STEP42(V, QB)                                                  \
  DTW_STEPQ2((V)[0], (QB))                                                 \
  DTW_STEPQ2((V)[1], (QB) + 1)                                             \
  DTW_STEPQ2((V)[2], (QB) + 2)                                             \
  DTW_STEPQ2((V)[3], (QB) + 3)

// dtw13's verified tile, reindexed per-half: hw = wave index within half,
// ring region rbase+hw-1 / rbase+hw, last wave of half writes rowhalf (LDS).
#define DTW_TILE14(SS, C0,C1,C2,C3,C4,C5,C6,C7,C8,C9,C10,C11,C12,C13,C14,C15, \
                       N0,N1,N2,N3,N4,N5,N6,N7,N8,N9,N10,N11,N12,N13,N14,N15) \
  {                                                                        \
    const int T0 = ((SS) - 3 * hw) * 64;                                   \
    if (T0 >= 0 && T0 < TS2) {                                             \
      const int LT = T0 >> 6;                                              \
      if (LT < NT2 - 1) {                                                  \
        const void* np_ = (const void*)(base + (size_t)(LT + 1) * 4096);   \
        GLOADO(N0,  np_, 0);    GLOADO(N1,  np_, 16);                      \
        GLOADO(N2,  np_, 32);   GLOADO(N3,  np_, 48);                      \
        GLOADO(N4,  np_, 64);   GLOADO(N5,  np_, 80);                      \
        GLOADO(N6,  np_, 96);   GLOADO(N7,  np_, 112);                     \
        GLOADO(N8,  np_, 128);  GLOADO(N9,  np_, 144);                     \
        GLOADO(N10, np_, 160);  GLOADO(N11, np_, 176);                     \
        GLOADO(N12, np_, 192);  GLOADO(N13, np_, 208);                     \
        GLOADO(N14, np_, 224);  GLOADO(N15, np_, 240);                     \
        asm volatile("s_waitcnt vmcnt(16)" ::: "memory");                  \
      } else {                                                             \
        asm volatile("s_waitcnt vmcnt(0)" ::: "memory");                   \
      }                                                                    \
      __builtin_amdgcn_sched_barrier(0);                                   \
      float rv, rvo;                                                       \
      if (hw0) { rv = BIGV; rvo = BIGV; }                                  \
      else {                                                               \
        rv  = ringbuf[rbase + hw - 1][(T0 + l) & (RB - 1)];                \
        rvo = (LT == 0) ? BIGV : ringbuf[rbase + hw - 1][(T0 - 1) & (RB - 1)]; \
      }                                                                    \
      float out = 0.f;                                                     \
      DTW_STEP42(C0, 0)   DTW_STEP42(C1, 4)   DTW_STEP42(C2, 8)            \
      DTW_STEP42(C3, 12)  DTW_STEP42(C4, 16)  DTW_STEP42(C5, 20)           \
      DTW_STEP42(C6, 24)  DTW_STEP42(C7, 28)  DTW_STEP42(C8, 32)           \
      DTW_STEP42(C9, 36)  DTW_STEP42(C10, 40) DTW_STEP42(C11, 44)          \
      DTW_STEP42(C12, 48) DTW_STEP42(C13, 52) DTW_STEP42(C14, 56)          \
      DTW_STEP42(C15, 60)                                                  \
      const int e_ = T0 - 127 + l;                                         \
      if ((unsigned)e_ < (unsigned)T_LEN) {                                \
        if (hwlast) rowhalf[e_] = out;                                     \
        else        ringbuf[rbase + hw][e_ & (RB - 1)] = out;              \
      }                                                                    \
    }                                                                      \
  }

__global__ __launch_bounds__(512)
void dtw14_kernel(const unsigned* __restrict__ dist, float* __restrict__ bres) {
  __shared__ float ringbuf[6][RB];     // regions 0-2 fwd, 3-5 bwd
  __shared__ float rowf[T_LEN];        // fwd(511, j)
  __shared__ float rowb[T_LEN];        // bwd'(511, j') = bwd(512, 1023-j')
  __shared__ float wmin[8];

  const int tid = threadIdx.x;
  const int b   = blockIdx.x;
  const int l   = tid & 63;
  const int w   = tid >> 6;                 // 0..7; 0-3 fwd, 4-7 bwd
  const int hw  = w & 3;                    // wave index within half
  const int rbase = (w < 4) ? 0 : 3;
  const bool lane0  = (l == 0);
  const bool lane63 = (l == 63);
  const bool hw0    = (hw == 0);
  const bool hwlast = (hw == 3);
  float* rowhalf = (w < 4) ? rowf : rowb;

  {
    float* rp = &ringbuf[0][0];
    for (int k = tid; k < 6 * RB; k += 512) rp[k] = BIGV;
  }

  // dist slot = w (slot = h*4+hw = (w>>2)*4 + (w&3) = w)
  const unsigned* base = dist + (size_t)(b * 8 + w) * NT2 * 4096 + l * 64;

  u32x4 a0,a1,a2,a3,a4,a5,a6,a7,a8,a9,a10,a11,a12,a13,a14,a15;
  u32x4 b0,b1,b2,b3,b4,b5,b6,b7,b8,b9,b10,b11,b12,b13,b14,b15;
  {
    const void* tp = (const void*)base;     // this wave's tile 0
    GLOADO(a0,  tp, 0);    GLOADO(a1,  tp, 16);
    GLOADO(a2,  tp, 32);   GLOADO(a3,  tp, 48);
    GLOADO(a4,  tp, 64);   GLOADO(a5,  tp, 80);
    GLOADO(a6,  tp, 96);   GLOADO(a7,  tp, 112);
    GLOADO(a8,  tp, 128);  GLOADO(a9,  tp, 144);
    GLOADO(a10, tp, 160);  GLOADO(a11, tp, 176);
    GLOADO(a12, tp, 192);  GLOADO(a13, tp, 208);
    GLOADO(a14, tp, 224);  GLOADO(a15, tp, 240);
    asm volatile("s_waitcnt vmcnt(0)" ::: "memory");
    __builtin_amdgcn_sched_barrier(0);
  }
  // copy makes odd-lag waves (hw=1,3) start correctly from buffer B (R9/R18-verified)
  b0=a0; b1=a1; b2=a2; b3=a3; b4=a4; b5=a5; b6=a6; b7=a7;
  b8=a8; b9=a9; b10=a10; b11=a11; b12=a12; b13=a13; b14=a14; b15=a15;

  __syncthreads();   // covers ring-init

  float aC = BIGV, aP = BIGV, bC = BIGV, bP = BIGV;

  for (int ss = 0; ss < NSS1; ss += 2) {
    DTW_TILE14(ss,     a0,a1,a2,a3,a4,a5,a6,a7,a8,a9,a10,a11,a12,a13,a14,a15,
                       b0,b1,b2,b3,b4,b5,b6,b7,b8,b9,b10,b11,b12,b13,b14,b15)
    __syncthreads();
    DTW_TILE14(ss + 1, b0,b1,b2,b3,b4,b5,b6,b7,b8,b9,b10,b11,b12,b13,b14,b15,
                       a0,a1,a2,a3,a4,a5,a6,a7,a8,a9,a10,a11,a12,a13,a14,a15)
    __syncthreads();
  }
  (void)aP; (void)bP;

  // in-block combine (R12-verified algebra, deterministic reduction):
  // bres[b] = min_j rowf[j] + min(bwd(512,j), bwd(512,j+1)), bwd(512,j)=rowb[1023-j]
  {
    float vmn = BIGV;
#pragma unroll
    for (int r = 0; r < 2; ++r) {
      const int j = tid + r * 512;
      float b1v = rowb[1023 - j];
      float b2v = (j < 1023) ? rowb[1022 - j] : BIGV;
      float v = rowf[j] + fminf(b1v, b2v);
      vmn = fminf(vmn, v);
    }
    for (int m = 1; m < 64; m <<= 1) vmn = fminf(vmn, __shfl_xor(vmn, m, 64));
    if (lane0) wmin[w] = vmn;
    __syncthreads();
    if (tid == 0) {
      float m = wmin[0];
      for (int i = 1; i < 8; ++i) m = fminf(m, wmin[i]);
      bres[b] = m;
    }
  }
}

__global__ void mean_kernel(const float* __restrict__ bres, float* __restrict__ out, int B) {
  if (threadIdx.x == 0) {
    float s = 0.f;
    for (int i = 0; i < B; ++i) s += bres[i];
    out[0] = s / (float)B;
  }
}

// ===========================================================================
// TIER 2 (R15-verified): dist4 + dtw11 + combine + mean.
// ===========================================================================
__global__ __launch_bounds__(256)
void dist4_kernel(const float* __restrict__ obs, const float* __restrict__ mod,
                  _Float16* __restrict__ dist) {
  const int q  = threadIdx.x & 63;
  const int wv = threadIdx.x >> 6;
  const int lt = blockIdx.x % NTILE;
  const int lg = blockIdx.x / NTILE;
  const int l  = lg * 4 + wv;
  const int s  = blockIdx.y;
  const int b  = blockIdx.z;
  const int t  = lt * 64 + q;
  const int cloc = t - l;
  const int row  = (s < 8) ? (64 * s + l) : (1023 - (64 * (s - 8) + l));

  float dd = __builtin_inff();
  if ((unsigned)cloc < (unsigned)T_LEN) {
    const int cg = (s < 8) ? cloc : (1023 - cloc);
    const float4* o4 = (const float4*)(obs + ((size_t)b * T_LEN + row) * D_DIM);
    const float4* m4 = (const float4*)(mod + ((size_t)b * T_LEN + cg) * D_DIM);
    float4 a0 = o4[0], a1 = o4[1], c0 = m4[0], c1 = m4[1];
    float acc = 0.f, df;
    df = a0.x - c0.x + EPSV; acc = fmaf(df, df, acc);
    df = a0.y - c0.y + EPSV; acc = fmaf(df, df, acc);
    df = a0.z - c0.z + EPSV; acc = fmaf(df, df, acc);
    df = a0.w - c0.w + EPSV; acc = fmaf(df, df, acc);
    df = a1.x - c1.x + EPSV; acc = fmaf(df, df, acc);
    df = a1.y - c1.y + EPSV; acc = fmaf(df, df, acc);
    df = a1.z - c1.z + EPSV; acc = fmaf(df, df, acc);
    df = a1.w - c1.w + EPSV; acc = fmaf(df, df, acc);
    dd = sqrtf(acc);
  }
  dist[(((size_t)(b * NSLOT + s) * NTILE + lt) * 64 + l) * 64 + q] = (_Float16)dd;
}

#define DTW_STEPX(DD, Q)                                                   \
  {                                                                        \
    const float dd_ = (DD);                                                \
    float cu = dpp_shr1(c);                                                \
    cu = lane0 ? rv : cu;                                                  \
    float best = fminf(fminf(cu, cuPrev), c);                              \
    if ((Q) == 0 && LT == 0) { if (w0 && lane0) best = 0.f; }              \
    float cv = dd_ + best;                                                 \
    cuPrev = cu;                                                           \
    c = cv;                                                                \
    rv = dpp_shl1(rv);                                                     \
    out = dpp_shl1(out);                                                   \
    out = lane63 ? c : out;                                                \
  }

#define DTW_STEP2X(U, QB)                                                  \
  {                                                                        \
    half2v hh_ = __builtin_bit_cast(half2v, (unsigned)(U));                \
    DTW_STEPX((float)hh_[0], (QB))                                         \
    DTW_STEPX((float)hh_[1], (QB) + 1)                                     \
  }

#define DTW_STEP8X(V, QB)                                                  \
  DTW_STEP2X((V)[0], (QB))                                                 \
  DTW_STEP2X((V)[1], (QB) + 2)                                             \
  DTW_STEP2X((V)[2], (QB) + 4)                                             \
  DTW_STEP2X((V)[3], (QB) + 6)

#define DTW_TILEX(SS, C0, C1, C2, C3, C4, C5, C6, C7,                      \
                      N0, N1, N2, N3, N4, N5, N6, N7)                      \
  {                                                                        \
    const int T0 = ((SS) - 2 * w) * 64;                                    \
    if (T0 >= 0 && T0 < TSTEPS) {                                          \
      const int LT = T0 >> 6;                                              \
      if (LT < NTILE - 1) {                                                \
        const void* np_ = (const void*)(base + (size_t)(LT + 1) * 4096);   \
        GLOADO(N0, np_, 0);   GLOADO(N1, np_, 16);                         \
        GLOADO(N2, np_, 32);  GLOADO(N3, np_, 48);                         \
        GLOADO(N4, np_, 64);  GLOADO(N5, np_, 80);                         \
        GLOADO(N6, np_, 96);  GLOADO(N7, np_, 112);                        \
        asm volatile("s_waitcnt vmcnt(8)" ::: "memory");                   \
      } else {                                                             \
        asm volatile("s_waitcnt vmcnt(0)" ::: "memory");                   \
      }                                                                    \
      __builtin_amdgcn_sched_barrier(0);                                   \
      float rv;                                                            \
      if (w0) { rv = BIGV; }                                               \
      else    { rv = ringbuf[w - 1][(T0 + l) & (RB - 1)]; }                \
      float out = 0.f;                                                     \
      DTW_STEP8X(C0, 0)  DTW_STEP8X(C1, 8)  DTW_STEP8X(C2, 16)             \
      DTW_STEP8X(C3, 24) DTW_STEP8X(C4, 32) DTW_STEP8X(C5, 40)             \
      DTW_STEP8X(C6, 48) DTW_STEP8X(C7, 56)                                \
      const int e_ = T0 - 63 + l;                                          \
      if ((unsigned)e_ < (unsigned)T_LEN) {                                \
        if (wlast) rowg[e_] = out;                                         \
        else       ringbuf[w][e_ & (RB - 1)] = out;                        \
      }                                                                    \
    }                                                                      \
  }

__global__ __launch_bounds__(512)
void dtw11_kernel(const _Float16* __restrict__ dist, float* __restrict__ rows) {
  __shared__ float ringbuf[NW3 - 1][RB];

  const int tid  = threadIdx.x;
  const int half = blockIdx.x;
  const int b    = blockIdx.y;
  const int l    = tid & 63;
  const int w    = tid >> 6;
  const bool lane0  = (l == 0);
  const bool lane63 = (l == 63);
  const bool w0     = (w == 0);
  const bool wlast  = (w == NW3 - 1);
  const int  s      = half * 8 + w;

  float* rowg = rows + ((size_t)b * 2 + half) * T_LEN;

  {
    float* rp = &ringbuf[0][0];
    for (int k = tid; k < (NW3 - 1) * RB; k += 512) rp[k] = BIGV;
  }

  const _Float16* base = dist + (size_t)(b * NSLOT + s) * NTILE * 4096 + l * 64;

  u32x4 a0, a1, a2, a3, a4, a5, a6, a7;
  u32x4 b0, b1, b2, b3, b4, b5, b6, b7;
  {
    const void* tp = (const void*)base;
    GLOADO(a0, tp, 0);   GLOADO(a1, tp, 16);
    GLOADO(a2, tp, 32);  GLOADO(a3, tp, 48);
    GLOADO(a4, tp, 64);  GLOADO(a5, tp, 80);
    GLOADO(a6, tp, 96);  GLOADO(a7, tp, 112);
    asm volatile("s_waitcnt vmcnt(0)" ::: "memory");
    __builtin_amdgcn_sched_barrier(0);
  }
  b0 = a0; b1 = a1; b2 = a2; b3 = a3; b4 = a4; b5 = a5; b6 = a6; b7 = a7;

  __syncthreads();

  float c = BIGV, cuPrev = BIGV;

  for (int ss = 0; ss < NSS3; ss += 2) {
    DTW_TILEX(ss,     a0, a1, a2, a3, a4, a5, a6, a7,
                      b0, b1, b2, b3, b4, b5, b6, b7)
    __syncthreads();
    DTW_TILEX(ss + 1, b0, b1, b2, b3, b4, b5, b6, b7,
                      a0, a1, a2, a3, a4, a5, a6, a7)
    __syncthreads();
  }
}

__global__ __launch_bounds__(1024)
void combine_kernel(const float* __restrict__ rows, float* __restrict__ bres) {
  __shared__ unsigned gmin;
  const int b = blockIdx.x;
  const int tid = threadIdx.x;
  if (tid == 0) gmin = 0x7f800000u;
  __syncthreads();
  const float* rowf = rows + (size_t)b * 2 * T_LEN;
  const float* rowb = rowf + T_LEN;
  const int j = tid;
  float b1v = rowb[1023 - j];
  float b2v = (j < 1023) ? rowb[1022 - j] : BIGV;
  float v = rowf[j] + fminf(b1v, b2v);
  for (int m = 1; m < 64; m <<= 1) v = fminf(v, __shfl_xor(v, m, 64));
  if ((tid & 63) == 0) atomicMin(&gmin, __float_as_uint(v));  // v>0
  __syncthreads();
  if (tid == 0) bres[b] = __uint_as_float(gmin);
}

// ===========================================================================
// TIER 3 (R2-verified): fused distance fallback.
// ===========================================================================
#define NWAVE  16
#define NSS    47
__global__ __launch_bounds__(1024)
void dtw_fused_kernel(const float* __restrict__ obs, const float* __restrict__ mod,
                      float* __restrict__ bres) {
  __shared__ float ringbuf2[NWAVE - 1][RB];
  __shared__ float modl[T_LEN * D_DIM];

  const int tid = threadIdx.x;
  const int b   = blockIdx.x;
  const int l   = tid & 63;
  const int w   = tid >> 6;

  const float4* msrc = (const float4*)(mod + (size_t)b * T_LEN * D_DIM);
  float4* mdst = (float4*)modl;
  mdst[tid]        = msrc[tid];
  mdst[tid + 1024] = msrc[tid + 1024];
  const float* orow = obs + ((size_t)b * T_LEN + w * 64 + l) * D_DIM;
  float4 a0 = ((const float4*)orow)[0];
  float4 a1 = ((const float4*)orow)[1];
  float obsp[8] = {a0.x + EPSV, a0.y + EPSV, a0.z + EPSV, a0.w + EPSV,
                   a1.x + EPSV, a1.y + EPSV, a1.z + EPSV, a1.w + EPSV};
  float mrow[8] = {0.f, 0.f, 0.f, 0.f, 0.f, 0.f, 0.f, 0.f};
  __syncthreads();

  float c = BIGV, p = BIGV, rprev = BIGV;
  const bool lane0  = (l == 0);
  const bool lane63 = (l == 63);
  const int  rdw    = (w > 0) ? (w - 1) : 0;
  const bool w0     = (w == 0);
  const bool wlast  = (w == NWAVE - 1);

  for (int ss = 0; ss < NSS; ++ss) {
    const int t0 = (ss - 2 * w) * 64;
    if (t0 >= 0 && t0 < TSTEPS) {
#pragma unroll 8
      for (int q = 0; q < 64; ++q) {
        const int t = t0 + q;
#pragma unroll
        for (int d = 0; d < 8; ++d) mrow[d] = dpp_shr1(mrow[d]);
        if (lane0) {
          const int tm = (t < T_LEN) ? t : (T_LEN - 1);
          const float4* mr = (const float4*)(modl + tm * 8);
          float4 m0 = mr[0], m1 = mr[1];
          mrow[0] = m0.x; mrow[1] = m0.y; mrow[2] = m0.z; mrow[3] = m0.w;
          mrow[4] = m1.x; mrow[5] = m1.y; mrow[6] = m1.z; mrow[7] = m1.w;
        }
        float acc = 0.f;
#pragma unroll
        for (int d = 0; d < 8; ++d) { float df = obsp[d] - mrow[d]; acc = fmaf(df, df, acc); }
        float dd = sqrtf(acc);

        float c_up = dpp_shr1(c);
        float p_up = dpp_shr1(p);
        float ringv = ringbuf2[rdw][t & (RB - 1)];
        if (lane0) { c_up = w0 ? BIGV : ringv; p_up = w0 ? BIGV : rprev; }
        rprev = ringv;

        const int j = t - l;
        const bool valid = ((unsigned)j < (unsigned)T_LEN);
        float best = fminf(fminf(c_up, p_up), c);
        if (w0 && t == 0) { if (lane0) best = 0.f; }
        float cur = valid ? (dd + best) : BIGV;
        p = c; c = cur;

        if (lane63 && !wlast && t >= 63 && t < TSTEPS - 1)
          ringbuf2[w][(t - 63) & (RB - 1)] = c;
      }
    }
    __syncthreads();
  }
  if (tid == 1023) bres[b] = p;
}

extern "C" void kernel_launch(void* const* d_in, const int* in_sizes, int n_in,
                              void* d_out, int out_size, void* d_ws, size_t ws_size,
                              hipStream_t stream) {
  (void)n_in; (void)out_size;
  const float* obs = (const float*)d_in[0];
  const float* mod = (const float*)d_in[1];
  float* out = (float*)d_out;
  const int B = in_sizes[0] / (T_LEN * D_DIM);

  float* bres = (float*)d_ws;                                  // B floats
  float* rows = (float*)((char*)d_ws + 256);                   // B*2*1024 floats (tier-2)
  char*  dist = (char*)d_ws + 256 + (size_t)B * 2 * T_LEN * 4;
  const size_t need1 = 256 + (size_t)B * 2 * T_LEN * 4
                     + (size_t)B * 8 * NT2 * 4096 * 4;             // u32/step
  const size_t need2 = 256 + (size_t)B * 2 * T_LEN * 4
                     + (size_t)B * NSLOT * NTILE * 4096 * sizeof(_Float16);

  if (ws_size >= need1) {
    dist6_kernel<<<dim3(NT2 * 16, 8, B), 256, 0, stream>>>(obs, mod, (unsigned*)dist);
    dtw14_kernel<<<B, 512, 0, stream>>>((const unsigned*)dist, bres);
    mean_kernel<<<1, 64, 0, stream>>>(bres, out, B);
  } else if (ws_size >= need2) {
    dist4_kernel<<<dim3(NTILE * 16, NSLOT, B), 256, 0, stream>>>(obs, mod, (_Float16*)dist);
    dtw11_kernel<<<dim3(2, B), 512, 0, stream>>>((const _Float16*)dist, rows);
    combine_kernel<<<B, 1024, 0, stream>>>(rows, bres);
    mean_kernel<<<1, 64, 0, stream>>>(bres, out, B);
  } else {
    dtw_fused_kernel<<<B, 1024, 0, stream>>>(obs, mod, bres);
    mean_kernel<<<1, 64, 0, stream>>>(bres, out, B);
  }
}

// Round 20
// 93.501 us; speedup vs baseline: 1.3825x; 1.3825x over previous
//
#include <hip/hip_runtime.h>

#define T_LEN  1024
#define D_DIM  8
#define BIGV   1e30f
#define EPSV   1e-6f
#define RB     256
#define NTILE  17          // tiles per half-strip (1088 local steps)
#define TSTEPS 1088
#define NSLOT  16          // 8 fwd + 8 bwd wave slots
#define NW3    8           // waves per half-block
#define NSS3   32          // 2*7 + 17 = 31, padded even

typedef _Float16 half2v __attribute__((ext_vector_type(2)));
typedef unsigned u32x4  __attribute__((ext_vector_type(4)));

__device__ __forceinline__ float dpp_shr1(float x) {   // dst[n]=src[n-1]; lane0 keeps old
  int xi = __builtin_bit_cast(int, x);
  int r = __builtin_amdgcn_update_dpp(xi, xi, 0x138, 0xf, 0xf, false);
  return __builtin_bit_cast(float, r);
}
__device__ __forceinline__ float dpp_shl1(float x) {   // dst[n]=src[n+1]; lane63 keeps old
  int xi = __builtin_bit_cast(int, x);
  int r = __builtin_amdgcn_update_dpp(xi, xi, 0x130, 0xf, 0xf, false);
  return __builtin_bit_cast(float, r);
}

#define GLOADO(dst, addr, OFF)                                             \
  asm volatile("global_load_dwordx4 %0, %1, off offset:" #OFF             \
               : "=v"(dst) : "v"(addr))

// ---------------------------------------------------------------------------
// dist4 (R15-verified): dist[b][s][lt][l][q] fp16, s = wave slot.
//   s<8  (fwd): row = 64s+l,            col = t-l          (t = 64 lt + q)
//   s>=8 (bwd): row = 1023-(64(s-8)+l), col = 1023-(t-l)
// OOB local col -> +inf.
// ---------------------------------------------------------------------------
__global__ __launch_bounds__(256)
void dist4_kernel(const float* __restrict__ obs, const float* __restrict__ mod,
                  _Float16* __restrict__ dist) {
  const int q  = threadIdx.x & 63;
  const int wv = threadIdx.x >> 6;           // 0..3
  const int lt = blockIdx.x % NTILE;
  const int lg = blockIdx.x / NTILE;         // 0..15
  const int l  = lg * 4 + wv;
  const int s  = blockIdx.y;                 // 0..15
  const int b  = blockIdx.z;
  const int t  = lt * 64 + q;
  const int cloc = t - l;
  const int row  = (s < 8) ? (64 * s + l) : (1023 - (64 * (s - 8) + l));

  float dd = __builtin_inff();
  if ((unsigned)cloc < (unsigned)T_LEN) {
    const int cg = (s < 8) ? cloc : (1023 - cloc);
    const float4* o4 = (const float4*)(obs + ((size_t)b * T_LEN + row) * D_DIM);
    const float4* m4 = (const float4*)(mod + ((size_t)b * T_LEN + cg) * D_DIM);
    float4 a0 = o4[0], a1 = o4[1], c0 = m4[0], c1 = m4[1];
    float acc = 0.f, df;
    df = a0.x - c0.x + EPSV; acc = fmaf(df, df, acc);
    df = a0.y - c0.y + EPSV; acc = fmaf(df, df, acc);
    df = a0.z - c0.z + EPSV; acc = fmaf(df, df, acc);
    df = a0.w - c0.w + EPSV; acc = fmaf(df, df, acc);
    df = a1.x - c1.x + EPSV; acc = fmaf(df, df, acc);
    df = a1.y - c1.y + EPSV; acc = fmaf(df, df, acc);
    df = a1.z - c1.z + EPSV; acc = fmaf(df, df, acc);
    df = a1.w - c1.w + EPSV; acc = fmaf(df, df, acc);
    dd = sqrtf(acc);
  }
  dist[(((size_t)(b * NSLOT + s) * NTILE + lt) * 64 + l) * 64 + q] = (_Float16)dd;
}

// ---------------------------------------------------------------------------
// dtw11 (R15-verified): 1 row/lane, 8 waves/half, halves on separate blocks,
// cuPrev identity, batched ring read + dpp rotate, batched boundary publish,
// asm dwordx4 double-buffer with counted vmcnt.
// ---------------------------------------------------------------------------
#define DTW_STEPX(DD, Q)                                                   \
  {                                                                        \
    const float dd_ = (DD);                                                \
    float cu = dpp_shr1(c);                                                \
    cu = lane0 ? rv : cu;                                                  \
    float best = fminf(fminf(cu, cuPrev), c);                              \
    if ((Q) == 0 && LT == 0) { if (w0 && lane0) best = 0.f; }              \
    float cv = dd_ + best;                                                 \
    cuPrev = cu;                                                           \
    c = cv;                                                                \
    rv = dpp_shl1(rv);                                                     \
    out = dpp_shl1(out);                                                   \
    out = lane63 ? c : out;                                                \
  }

#define DTW_STEP2X(U, QB)                                                  \
  {                                                                        \
    half2v hh_ = __builtin_bit_cast(half2v, (unsigned)(U));                \
    DTW_STEPX((float)hh_[0], (QB))                                         \
    DTW_STEPX((float)hh_[1], (QB) + 1)                                     \
  }

#define DTW_STEP8X(V, QB)                                                  \
  DTW_STEP2X((V)[0], (QB))                                                 \
  DTW_STEP2X((V)[1], (QB) + 2)                                             \
  DTW_STEP2X((V)[2], (QB) + 4)                                             \
  DTW_STEP2X((V)[3], (QB) + 6)

#define DTW_TILEX(SS, C0, C1, C2, C3, C4, C5, C6, C7,                      \
                      N0, N1, N2, N3, N4, N5, N6, N7)                      \
  {                                                                        \
    const int T0 = ((SS) - 2 * w) * 64;                                    \
    if (T0 >= 0 && T0 < TSTEPS) {                                          \
      const int LT = T0 >> 6;                                              \
      if (LT < NTILE - 1) {                                                \
        const void* np_ = (const void*)(base + (size_t)(LT + 1) * 4096);   \
        GLOADO(N0, np_, 0);   GLOADO(N1, np_, 16);                         \
        GLOADO(N2, np_, 32);  GLOADO(N3, np_, 48);                         \
        GLOADO(N4, np_, 64);  GLOADO(N5, np_, 80);                         \
        GLOADO(N6, np_, 96);  GLOADO(N7, np_, 112);                        \
        asm volatile("s_waitcnt vmcnt(8)" ::: "memory");                   \
      } else {                                                             \
        asm volatile("s_waitcnt vmcnt(0)" ::: "memory");                   \
      }                                                                    \
      __builtin_amdgcn_sched_barrier(0);                                   \
      float rv;                                                            \
      if (w0) { rv = BIGV; }                                               \
      else    { rv = ringbuf[w - 1][(T0 + l) & (RB - 1)]; }                \
      float out = 0.f;                                                     \
      DTW_STEP8X(C0, 0)  DTW_STEP8X(C1, 8)  DTW_STEP8X(C2, 16)             \
      DTW_STEP8X(C3, 24) DTW_STEP8X(C4, 32) DTW_STEP8X(C5, 40)             \
      DTW_STEP8X(C6, 48) DTW_STEP8X(C7, 56)                                \
      const int e_ = T0 - 63 + l;                                          \
      if ((unsigned)e_ < (unsigned)T_LEN) {                                \
        if (wlast) rowg[e_] = out;                                         \
        else       ringbuf[w][e_ & (RB - 1)] = out;                        \
      }                                                                    \
    }                                                                      \
  }

__global__ __launch_bounds__(512)
void dtw11_kernel(const _Float16* __restrict__ dist, float* __restrict__ rows) {
  __shared__ float ringbuf[NW3 - 1][RB];

  const int tid  = threadIdx.x;
  const int half = blockIdx.x;              // 0 = fwd, 1 = bwd
  const int b    = blockIdx.y;
  const int l    = tid & 63;
  const int w    = tid >> 6;                // 0..7
  const bool lane0  = (l == 0);
  const bool lane63 = (l == 63);
  const bool w0     = (w == 0);
  const bool wlast  = (w == NW3 - 1);
  const int  s      = half * 8 + w;         // dist slot

  float* rowg = rows + ((size_t)b * 2 + half) * T_LEN;

  {
    float* rp = &ringbuf[0][0];
    for (int k = tid; k < (NW3 - 1) * RB; k += 512) rp[k] = BIGV;
  }

  const _Float16* base = dist + (size_t)(b * NSLOT + s) * NTILE * 4096 + l * 64;

  u32x4 a0, a1, a2, a3, a4, a5, a6, a7;
  u32x4 b0, b1, b2, b3, b4, b5, b6, b7;
  {
    const void* tp = (const void*)base;     // this slot's tile 0
    GLOADO(a0, tp, 0);   GLOADO(a1, tp, 16);
    GLOADO(a2, tp, 32);  GLOADO(a3, tp, 48);
    GLOADO(a4, tp, 64);  GLOADO(a5, tp, 80);
    GLOADO(a6, tp, 96);  GLOADO(a7, tp, 112);
    asm volatile("s_waitcnt vmcnt(0)" ::: "memory");
    __builtin_amdgcn_sched_barrier(0);
  }
  b0 = a0; b1 = a1; b2 = a2; b3 = a3; b4 = a4; b5 = a5; b6 = a6; b7 = a7;

  __syncthreads();   // covers ring-init

  float c = BIGV, cuPrev = BIGV;

  for (int ss = 0; ss < NSS3; ss += 2) {
    DTW_TILEX(ss,     a0, a1, a2, a3, a4, a5, a6, a7,
                      b0, b1, b2, b3, b4, b5, b6, b7)
    __syncthreads();
    DTW_TILEX(ss + 1, b0, b1, b2, b3, b4, b5, b6, b7,
                      a0, a1, a2, a3, a4, a5, a6, a7)
    __syncthreads();
  }
}

// ---------------------------------------------------------------------------
// finish: out = mean_b [ min_j rowf[j] + min(bwd(512,j), bwd(512,j+1)) ]
//   rowf[j] = rows[b][0][j]; bwd(512,j) = rows[b][1][1023-j].
// Single block, deterministic (combine algebra R12/R15-verified).
// ---------------------------------------------------------------------------
__global__ __launch_bounds__(1024)
void finish_kernel(const float* __restrict__ rows, float* __restrict__ out, int B) {
  __shared__ float wmin[16];
  const int tid = threadIdx.x;
  float s = 0.f;
  for (int b = 0; b < B; ++b) {
    const float* rowf = rows + (size_t)b * 2 * T_LEN;
    const float* rowb = rowf + T_LEN;
    const int j = tid;
    float b1v = rowb[1023 - j];
    float b2v = (j < 1023) ? rowb[1022 - j] : BIGV;
    float v = rowf[j] + fminf(b1v, b2v);
    for (int m = 1; m < 64; m <<= 1) v = fminf(v, __shfl_xor(v, m, 64));
    if ((tid & 63) == 0) wmin[tid >> 6] = v;
    __syncthreads();
    if (tid == 0) {
      float m = wmin[0];
      for (int i = 1; i < 16; ++i) m = fminf(m, wmin[i]);
      s += m;
    }
    __syncthreads();
  }
  if (tid == 0) out[0] = s / (float)B;
}

// ---------------------------------------------------------------------------
// Fallback (no workspace): fused distance, per-step LDS ring (R2-verified).
// ---------------------------------------------------------------------------
#define NWAVE  16
#define NSS    47
__global__ __launch_bounds__(1024)
void dtw_fused_kernel(const float* __restrict__ obs, const float* __restrict__ mod,
                      float* __restrict__ bres) {
  __shared__ float ringbuf2[NWAVE - 1][RB];
  __shared__ float modl[T_LEN * D_DIM];

  const int tid = threadIdx.x;
  const int b   = blockIdx.x;
  const int l   = tid & 63;
  const int w   = tid >> 6;

  const float4* msrc = (const float4*)(mod + (size_t)b * T_LEN * D_DIM);
  float4* mdst = (float4*)modl;
  mdst[tid]        = msrc[tid];
  mdst[tid + 1024] = msrc[tid + 1024];
  const float* orow = obs + ((size_t)b * T_LEN + w * 64 + l) * D_DIM;
  float4 a0 = ((const float4*)orow)[0];
  float4 a1 = ((const float4*)orow)[1];
  float obsp[8] = {a0.x + EPSV, a0.y + EPSV, a0.z + EPSV, a0.w + EPSV,
                   a1.x + EPSV, a1.y + EPSV, a1.z + EPSV, a1.w + EPSV};
  float mrow[8] = {0.f, 0.f, 0.f, 0.f, 0.f, 0.f, 0.f, 0.f};
  __syncthreads();

  float c = BIGV, p = BIGV, rprev = BIGV;
  const bool lane0  = (l == 0);
  const bool lane63 = (l == 63);
  const int  rdw    = (w > 0) ? (w - 1) : 0;
  const bool w0     = (w == 0);
  const bool wlast  = (w == NWAVE - 1);

  for (int ss = 0; ss < NSS; ++ss) {
    const int t0 = (ss - 2 * w) * 64;
    if (t0 >= 0 && t0 < TSTEPS) {
#pragma unroll 8
      for (int q = 0; q < 64; ++q) {
        const int t = t0 + q;
#pragma unroll
        for (int d = 0; d < 8; ++d) mrow[d] = dpp_shr1(mrow[d]);
        if (lane0) {
          const int tm = (t < T_LEN) ? t : (T_LEN - 1);
          const float4* mr = (const float4*)(modl + tm * 8);
          float4 m0 = mr[0], m1 = mr[1];
          mrow[0] = m0.x; mrow[1] = m0.y; mrow[2] = m0.z; mrow[3] = m0.w;
          mrow[4] = m1.x; mrow[5] = m1.y; mrow[6] = m1.z; mrow[7] = m1.w;
        }
        float acc = 0.f;
#pragma unroll
        for (int d = 0; d < 8; ++d) { float df = obsp[d] - mrow[d]; acc = fmaf(df, df, acc); }
        float dd = sqrtf(acc);

        float c_up = dpp_shr1(c);
        float p_up = dpp_shr1(p);
        float ringv = ringbuf2[rdw][t & (RB - 1)];
        if (lane0) { c_up = w0 ? BIGV : ringv; p_up = w0 ? BIGV : rprev; }
        rprev = ringv;

        const int j = t - l;
        const bool valid = ((unsigned)j < (unsigned)T_LEN);
        float best = fminf(fminf(c_up, p_up), c);
        if (w0 && t == 0) { if (lane0) best = 0.f; }
        float cur = valid ? (dd + best) : BIGV;
        p = c; c = cur;

        if (lane63 && !wlast && t >= 63 && t < TSTEPS - 1)
          ringbuf2[w][(t - 63) & (RB - 1)] = c;
      }
    }
    __syncthreads();
  }
  if (tid == 1023) bres[b] = p;
}

__global__ void mean_kernel(const float* __restrict__ bres, float* __restrict__ out, int B) {
  if (threadIdx.x == 0) {
    float s = 0.f;
    for (int i = 0; i < B; ++i) s += bres[i];
    out[0] = s / (float)B;
  }
}

extern "C" void kernel_launch(void* const* d_in, const int* in_sizes, int n_in,
                              void* d_out, int out_size, void* d_ws, size_t ws_size,
                              hipStream_t stream) {
  (void)n_in; (void)out_size;
  const float* obs = (const float*)d_in[0];
  const float* mod = (const float*)d_in[1];
  float* out = (float*)d_out;
  const int B = in_sizes[0] / (T_LEN * D_DIM);

  float* bres = (float*)d_ws;                                  // B floats (tier-2)
  float* rows = (float*)((char*)d_ws + 256);                   // B*2*1024 floats
  _Float16* dist = (_Float16*)((char*)d_ws + 256 + (size_t)B * 2 * T_LEN * 4);
  const size_t need = 256 + (size_t)B * 2 * T_LEN * 4
                    + (size_t)B * NSLOT * NTILE * 4096 * sizeof(_Float16);

  if (ws_size >= need) {
    dist4_kernel<<<dim3(NTILE * 16, NSLOT, B), 256, 0, stream>>>(obs, mod, dist);
    dtw11_kernel<<<dim3(2, B), 512, 0, stream>>>(dist, rows);
    finish_kernel<<<1, 1024, 0, stream>>>(rows, out, B);
  } else {
    dtw_fused_kernel<<<B, 1024, 0, stream>>>(obs, mod, bres);
    mean_kernel<<<1, 64, 0, stream>>>(bres, out, B);
  }
}

// Round 21
// 89.167 us; speedup vs baseline: 1.4497x; 1.0486x over previous
//
#include <hip/hip_runtime.h>

#define T_LEN  1024
#define D_DIM  8
#define BIGV   1e30f
#define EPSV   1e-6f
#define RB     256
#define NTILE  17          // tiles per half-strip (1088 local steps)
#define TSTEPS 1088
#define NSLOT  16          // 8 fwd + 8 bwd wave slots
#define NW3    8           // waves per half-block
#define NSS3   32          // 2*7 + 17 = 31, padded even

typedef _Float16 half2v __attribute__((ext_vector_type(2)));
typedef unsigned u32x4  __attribute__((ext_vector_type(4)));

__device__ __forceinline__ float dpp_shr1(float x) {   // dst[n]=src[n-1]; lane0 keeps old
  int xi = __builtin_bit_cast(int, x);
  int r = __builtin_amdgcn_update_dpp(xi, xi, 0x138, 0xf, 0xf, false);
  return __builtin_bit_cast(float, r);
}
__device__ __forceinline__ float dpp_shl1(float x) {   // dst[n]=src[n+1]; lane63 keeps old
  int xi = __builtin_bit_cast(int, x);
  int r = __builtin_amdgcn_update_dpp(xi, xi, 0x130, 0xf, 0xf, false);
  return __builtin_bit_cast(float, r);
}
__device__ __forceinline__ float min3f(float a, float b, float c) {
  float r;
  asm("v_min3_f32 %0, %1, %2, %3" : "=v"(r) : "v"(a), "v"(b), "v"(c));
  return r;
}

#define GLOADO(dst, addr, OFF)                                             \
  asm volatile("global_load_dwordx4 %0, %1, off offset:" #OFF             \
               : "=v"(dst) : "v"(addr))

// ---------------------------------------------------------------------------
// dist4 (R15-verified): dist[b][s][lt][l][q] fp16, s = wave slot.
//   s<8  (fwd): row = 64s+l,            col = t-l          (t = 64 lt + q)
//   s>=8 (bwd): row = 1023-(64(s-8)+l), col = 1023-(t-l)
// OOB local col -> +inf.
// ---------------------------------------------------------------------------
__global__ __launch_bounds__(256)
void dist4_kernel(const float* __restrict__ obs, const float* __restrict__ mod,
                  _Float16* __restrict__ dist) {
  const int q  = threadIdx.x & 63;
  const int wv = threadIdx.x >> 6;           // 0..3
  const int lt = blockIdx.x % NTILE;
  const int lg = blockIdx.x / NTILE;         // 0..15
  const int l  = lg * 4 + wv;
  const int s  = blockIdx.y;                 // 0..15
  const int b  = blockIdx.z;
  const int t  = lt * 64 + q;
  const int cloc = t - l;
  const int row  = (s < 8) ? (64 * s + l) : (1023 - (64 * (s - 8) + l));

  float dd = __builtin_inff();
  if ((unsigned)cloc < (unsigned)T_LEN) {
    const int cg = (s < 8) ? cloc : (1023 - cloc);
    const float4* o4 = (const float4*)(obs + ((size_t)b * T_LEN + row) * D_DIM);
    const float4* m4 = (const float4*)(mod + ((size_t)b * T_LEN + cg) * D_DIM);
    float4 a0 = o4[0], a1 = o4[1], c0 = m4[0], c1 = m4[1];
    float acc = 0.f, df;
    df = a0.x - c0.x + EPSV; acc = fmaf(df, df, acc);
    df = a0.y - c0.y + EPSV; acc = fmaf(df, df, acc);
    df = a0.z - c0.z + EPSV; acc = fmaf(df, df, acc);
    df = a0.w - c0.w + EPSV; acc = fmaf(df, df, acc);
    df = a1.x - c1.x + EPSV; acc = fmaf(df, df, acc);
    df = a1.y - c1.y + EPSV; acc = fmaf(df, df, acc);
    df = a1.z - c1.z + EPSV; acc = fmaf(df, df, acc);
    df = a1.w - c1.w + EPSV; acc = fmaf(df, df, acc);
    dd = sqrtf(acc);
  }
  dist[(((size_t)(b * NSLOT + s) * NTILE + lt) * 64 + l) * 64 + q] = (_Float16)dd;
}

// ---------------------------------------------------------------------------
// dtw11 (R15-verified) with ONE delta: fminf(fminf(.)) -> v_min3_f32 asm.
// ---------------------------------------------------------------------------
#define DTW_STEPX(DD, Q)                                                   \
  {                                                                        \
    const float dd_ = (DD);                                                \
    float cu = dpp_shr1(c);                                                \
    cu = lane0 ? rv : cu;                                                  \
    float best = min3f(cu, cuPrev, c);                                     \
    if ((Q) == 0 && LT == 0) { if (w0 && lane0) best = 0.f; }              \
    float cv = dd_ + best;                                                 \
    cuPrev = cu;                                                           \
    c = cv;                                                                \
    rv = dpp_shl1(rv);                                                     \
    out = dpp_shl1(out);                                                   \
    out = lane63 ? c : out;                                                \
  }

#define DTW_STEP2X(U, QB)                                                  \
  {                                                                        \
    half2v hh_ = __builtin_bit_cast(half2v, (unsigned)(U));                \
    DTW_STEPX((float)hh_[0], (QB))                                         \
    DTW_STEPX((float)hh_[1], (QB) + 1)                                     \
  }

#define DTW_STEP8X(V, QB)                                                  \
  DTW_STEP2X((V)[0], (QB))                                                 \
  DTW_STEP2X((V)[1], (QB) + 2)                                             \
  DTW_STEP2X((V)[2], (QB) + 4)                                             \
  DTW_STEP2X((V)[3], (QB) + 6)

#define DTW_TILEX(SS, C0, C1, C2, C3, C4, C5, C6, C7,                      \
                      N0, N1, N2, N3, N4, N5, N6, N7)                      \
  {                                                                        \
    const int T0 = ((SS) - 2 * w) * 64;                                    \
    if (T0 >= 0 && T0 < TSTEPS) {                                          \
      const int LT = T0 >> 6;                                              \
      if (LT < NTILE - 1) {                                                \
        const void* np_ = (const void*)(base + (size_t)(LT + 1) * 4096);   \
        GLOADO(N0, np_, 0);   GLOADO(N1, np_, 16);                         \
        GLOADO(N2, np_, 32);  GLOADO(N3, np_, 48);                         \
        GLOADO(N4, np_, 64);  GLOADO(N5, np_, 80);                         \
        GLOADO(N6, np_, 96);  GLOADO(N7, np_, 112);                        \
        asm volatile("s_waitcnt vmcnt(8)" ::: "memory");                   \
      } else {                                                             \
        asm volatile("s_waitcnt vmcnt(0)" ::: "memory");                   \
      }                                                                    \
      __builtin_amdgcn_sched_barrier(0);                                   \
      float rv;                                                            \
      if (w0) { rv = BIGV; }                                               \
      else    { rv = ringbuf[w - 1][(T0 + l) & (RB - 1)]; }                \
      float out = 0.f;                                                     \
      DTW_STEP8X(C0, 0)  DTW_STEP8X(C1, 8)  DTW_STEP8X(C2, 16)             \
      DTW_STEP8X(C3, 24) DTW_STEP8X(C4, 32) DTW_STEP8X(C5, 40)             \
      DTW_STEP8X(C6, 48) DTW_STEP8X(C7, 56)                                \
      const int e_ = T0 - 63 + l;                                          \
      if ((unsigned)e_ < (unsigned)T_LEN) {                                \
        if (wlast) rowg[e_] = out;                                         \
        else       ringbuf[w][e_ & (RB - 1)] = out;                        \
      }                                                                    \
    }                                                                      \
  }

__global__ __launch_bounds__(512)
void dtw11_kernel(const _Float16* __restrict__ dist, float* __restrict__ rows) {
  __shared__ float ringbuf[NW3 - 1][RB];

  const int tid  = threadIdx.x;
  const int half = blockIdx.x;              // 0 = fwd, 1 = bwd
  const int b    = blockIdx.y;
  const int l    = tid & 63;
  const int w    = tid >> 6;                // 0..7
  const bool lane0  = (l == 0);
  const bool lane63 = (l == 63);
  const bool w0     = (w == 0);
  const bool wlast  = (w == NW3 - 1);
  const int  s      = half * 8 + w;         // dist slot

  float* rowg = rows + ((size_t)b * 2 + half) * T_LEN;

  {
    float* rp = &ringbuf[0][0];
    for (int k = tid; k < (NW3 - 1) * RB; k += 512) rp[k] = BIGV;
  }

  const _Float16* base = dist + (size_t)(b * NSLOT + s) * NTILE * 4096 + l * 64;

  u32x4 a0, a1, a2, a3, a4, a5, a6, a7;
  u32x4 b0, b1, b2, b3, b4, b5, b6, b7;
  {
    const void* tp = (const void*)base;     // this slot's tile 0
    GLOADO(a0, tp, 0);   GLOADO(a1, tp, 16);
    GLOADO(a2, tp, 32);  GLOADO(a3, tp, 48);
    GLOADO(a4, tp, 64);  GLOADO(a5, tp, 80);
    GLOADO(a6, tp, 96);  GLOADO(a7, tp, 112);
    asm volatile("s_waitcnt vmcnt(0)" ::: "memory");
    __builtin_amdgcn_sched_barrier(0);
  }
  b0 = a0; b1 = a1; b2 = a2; b3 = a3; b4 = a4; b5 = a5; b6 = a6; b7 = a7;

  __syncthreads();   // covers ring-init

  float c = BIGV, cuPrev = BIGV;

  for (int ss = 0; ss < NSS3; ss += 2) {
    DTW_TILEX(ss,     a0, a1, a2, a3, a4, a5, a6, a7,
                      b0, b1, b2, b3, b4, b5, b6, b7)
    __syncthreads();
    DTW_TILEX(ss + 1, b0, b1, b2, b3, b4, b5, b6, b7,
                      a0, a1, a2, a3, a4, a5, a6, a7)
    __syncthreads();
  }
}

// ---------------------------------------------------------------------------
// combine (R15-verified): bres[b] = min_j rowf[j] + min(bwd(512,j), bwd(512,j+1))
//   rowf[j] = rows[b][0][j]; bwd(512,j) = rows[b][1][1023-j].
// ---------------------------------------------------------------------------
__global__ __launch_bounds__(1024)
void combine_kernel(const float* __restrict__ rows, float* __restrict__ bres) {
  __shared__ unsigned gmin;
  const int b = blockIdx.x;
  const int tid = threadIdx.x;
  if (tid == 0) gmin = 0x7f800000u;
  __syncthreads();
  const float* rowf = rows + (size_t)b * 2 * T_LEN;
  const float* rowb = rowf + T_LEN;
  const int j = tid;
  float b1v = rowb[1023 - j];
  float b2v = (j < 1023) ? rowb[1022 - j] : BIGV;
  float v = rowf[j] + fminf(b1v, b2v);
  for (int m = 1; m < 64; m <<= 1) v = fminf(v, __shfl_xor(v, m, 64));
  if ((tid & 63) == 0) atomicMin(&gmin, __float_as_uint(v));  // v>0: int order == float order
  __syncthreads();
  if (tid == 0) bres[b] = __uint_as_float(gmin);
}

__global__ void mean_kernel(const float* __restrict__ bres, float* __restrict__ out, int B) {
  if (threadIdx.x == 0) {
    float s = 0.f;
    for (int i = 0; i < B; ++i) s += bres[i];
    out[0] = s / (float)B;
  }
}

// ---------------------------------------------------------------------------
// Fallback (no workspace): fused distance, per-step LDS ring (R2-verified).
// ---------------------------------------------------------------------------
#define NWAVE  16
#define NSS    47
__global__ __launch_bounds__(1024)
void dtw_fused_kernel(const float* __restrict__ obs, const float* __restrict__ mod,
                      float* __restrict__ bres) {
  __shared__ float ringbuf2[NWAVE - 1][RB];
  __shared__ float modl[T_LEN * D_DIM];

  const int tid = threadIdx.x;
  const int b   = blockIdx.x;
  const int l   = tid & 63;
  const int w   = tid >> 6;

  const float4* msrc = (const float4*)(mod + (size_t)b * T_LEN * D_DIM);
  float4* mdst = (float4*)modl;
  mdst[tid]        = msrc[tid];
  mdst[tid + 1024] = msrc[tid + 1024];
  const float* orow = obs + ((size_t)b * T_LEN + w * 64 + l) * D_DIM;
  float4 a0 = ((const float4*)orow)[0];
  float4 a1 = ((const float4*)orow)[1];
  float obsp[8] = {a0.x + EPSV, a0.y + EPSV, a0.z + EPSV, a0.w + EPSV,
                   a1.x + EPSV, a1.y + EPSV, a1.z + EPSV, a1.w + EPSV};
  float mrow[8] = {0.f, 0.f, 0.f, 0.f, 0.f, 0.f, 0.f, 0.f};
  __syncthreads();

  float c = BIGV, p = BIGV, rprev = BIGV;
  const bool lane0  = (l == 0);
  const bool lane63 = (l == 63);
  const int  rdw    = (w > 0) ? (w - 1) : 0;
  const bool w0     = (w == 0);
  const bool wlast  = (w == NWAVE - 1);

  for (int ss = 0; ss < NSS; ++ss) {
    const int t0 = (ss - 2 * w) * 64;
    if (t0 >= 0 && t0 < TSTEPS) {
#pragma unroll 8
      for (int q = 0; q < 64; ++q) {
        const int t = t0 + q;
#pragma unroll
        for (int d = 0; d < 8; ++d) mrow[d] = dpp_shr1(mrow[d]);
        if (lane0) {
          const int tm = (t < T_LEN) ? t : (T_LEN - 1);
          const float4* mr = (const float4*)(modl + tm * 8);
          float4 m0 = mr[0], m1 = mr[1];
          mrow[0] = m0.x; mrow[1] = m0.y; mrow[2] = m0.z; mrow[3] = m0.w;
          mrow[4] = m1.x; mrow[5] = m1.y; mrow[6] = m1.z; mrow[7] = m1.w;
        }
        float acc = 0.f;
#pragma unroll
        for (int d = 0; d < 8; ++d) { float df = obsp[d] - mrow[d]; acc = fmaf(df, df, acc); }
        float dd = sqrtf(acc);

        float c_up = dpp_shr1(c);
        float p_up = dpp_shr1(p);
        float ringv = ringbuf2[rdw][t & (RB - 1)];
        if (lane0) { c_up = w0 ? BIGV : ringv; p_up = w0 ? BIGV : rprev; }
        rprev = ringv;

        const int j = t - l;
        const bool valid = ((unsigned)j < (unsigned)T_LEN);
        float best = fminf(fminf(c_up, p_up), c);
        if (w0 && t == 0) { if (lane0) best = 0.f; }
        float cur = valid ? (dd + best) : BIGV;
        p = c; c = cur;

        if (lane63 && !wlast && t >= 63 && t < TSTEPS - 1)
          ringbuf2[w][(t - 63) & (RB - 1)] = c;
      }
    }
    __syncthreads();
  }
  if (tid == 1023) bres[b] = p;
}

extern "C" void kernel_launch(void* const* d_in, const int* in_sizes, int n_in,
                              void* d_out, int out_size, void* d_ws, size_t ws_size,
                              hipStream_t stream) {
  (void)n_in; (void)out_size;
  const float* obs = (const float*)d_in[0];
  const float* mod = (const float*)d_in[1];
  float* out = (float*)d_out;
  const int B = in_sizes[0] / (T_LEN * D_DIM);

  float* bres = (float*)d_ws;                                  // B floats
  float* rows = (float*)((char*)d_ws + 256);                   // B*2*1024 floats
  _Float16* dist = (_Float16*)((char*)d_ws + 256 + (size_t)B * 2 * T_LEN * 4);
  const size_t need = 256 + (size_t)B * 2 * T_LEN * 4
                    + (size_t)B * NSLOT * NTILE * 4096 * sizeof(_Float16);

  if (ws_size >= need) {
    dist4_kernel<<<dim3(NTILE * 16, NSLOT, B), 256, 0, stream>>>(obs, mod, dist);
    dtw11_kernel<<<dim3(2, B), 512, 0, stream>>>(dist, rows);
    combine_kernel<<<B, 1024, 0, stream>>>(rows, bres);
    mean_kernel<<<1, 64, 0, stream>>>(bres, out, B);
  } else {
    dtw_fused_kernel<<<B, 1024, 0, stream>>>(obs, mod, bres);
    mean_kernel<<<1, 64, 0, stream>>>(bres, out, B);
  }
}